// Round 1
// baseline (699.252 us; speedup 1.0000x reference)
//
#include <hip/hip_runtime.h>
#include <math.h>

#define N_NODES 16384
#define B_GRAPHS 8
#define NPG_     2048
#define E_EDGES  262144
#define F_IN  128
#define F_HID 256
#define F_OUT 128
#define ICP_IT 10
#define NN_BPG 32   // blocks per graph in NN-style kernels (64 src pts/block, 4-way tgt split)

// ---------------- CSR build ----------------
__global__ void k_count(const int* __restrict__ col, int* __restrict__ counts) {
    int e = blockIdx.x * 256 + threadIdx.x;
    if (e < E_EDGES) atomicAdd(&counts[col[e]], 1);
}

__global__ __launch_bounds__(1024) void k_scan(const int* __restrict__ counts,
        int* __restrict__ offs, int* __restrict__ cursor, float* __restrict__ dinv)
{
    __shared__ int sums[1024];
    const int t = threadIdx.x;
    const int base = t * 16;
    int local[16];
    int s = 0;
#pragma unroll
    for (int i = 0; i < 16; i++) { local[i] = counts[base + i]; s += local[i]; }
    sums[t] = s;
    __syncthreads();
    for (int o = 1; o < 1024; o <<= 1) {
        int v = 0;
        if (t >= o) v = sums[t - o];
        __syncthreads();
        sums[t] += v;
        __syncthreads();
    }
    int run = (t == 0) ? 0 : sums[t - 1];
#pragma unroll
    for (int i = 0; i < 16; i++) {
        offs[base + i]   = run;
        cursor[base + i] = run;
        dinv[base + i]   = rsqrtf((float)(local[i] + 1));  // deg = indeg + self loop
        run += local[i];
    }
    if (t == 1023) offs[N_NODES] = run;
}

__global__ void k_scatter(const int* __restrict__ row, const int* __restrict__ col,
        int* __restrict__ cursor, const float* __restrict__ dinv,
        int* __restrict__ srcid, float* __restrict__ normv)
{
    int e = blockIdx.x * 256 + threadIdx.x;
    if (e >= E_EDGES) return;
    int r = row[e], c = col[e];
    int p = atomicAdd(&cursor[c], 1);
    srcid[p] = r;
    normv[p] = dinv[r] * dinv[c];
}

// ---------------- GCN aggregation:  Y[c] = sum_{(r,c)} X[r]*norm + X[c]*dinv[c]^2 (+bias,relu) ----------------
template<int W>
__global__ void k_aggregate(const float* __restrict__ X, float* __restrict__ Y,
        const int* __restrict__ offs, const int* __restrict__ srcid,
        const float* __restrict__ normv, const float* __restrict__ dinv,
        const float* __restrict__ bias, int relu)
{
    const int n = blockIdx.x;
    const int j = threadIdx.x;
    float di = dinv[n];
    float acc = X[(size_t)n * W + j] * di * di;
    const int p1 = offs[n + 1];
    for (int p = offs[n]; p < p1; ++p) {
        acc = fmaf(X[(size_t)srcid[p] * W + j], normv[p], acc);
    }
    if (bias) acc += bias[j];
    if (relu) acc = fmaxf(acc, 0.f);
    Y[(size_t)n * W + j] = acc;
}

// ---------------- fp32 tiled GEMM: C[M,N] = A[M,K]@B[K,N] (+bias,relu) ----------------
__global__ __launch_bounds__(256) void k_gemm(const float* __restrict__ A,
        const float* __restrict__ B, const float* __restrict__ bias,
        float* __restrict__ C, int M, int N, int K, int relu)
{
    __shared__ float As[16][65];
    __shared__ float Bs[16][64];
    const int bm = blockIdx.y * 64;
    const int bn = blockIdx.x * 64;
    const int tid = threadIdx.x;
    const int tx = tid & 15;
    const int ty = tid >> 4;
    float acc[4][4];
#pragma unroll
    for (int r = 0; r < 4; r++)
#pragma unroll
        for (int c = 0; c < 4; c++) acc[r][c] = 0.f;

    for (int k0 = 0; k0 < K; k0 += 16) {
#pragma unroll
        for (int i = tid; i < 64 * 16; i += 256) {
            int m = i >> 4, kk = i & 15;
            As[kk][m] = A[(size_t)(bm + m) * K + (k0 + kk)];
        }
#pragma unroll
        for (int i = tid; i < 16 * 64; i += 256) {
            int kk = i >> 6, nn = i & 63;
            Bs[kk][nn] = B[(size_t)(k0 + kk) * N + (bn + nn)];
        }
        __syncthreads();
#pragma unroll
        for (int kk = 0; kk < 16; ++kk) {
            float a0 = As[kk][ty * 4 + 0], a1 = As[kk][ty * 4 + 1];
            float a2 = As[kk][ty * 4 + 2], a3 = As[kk][ty * 4 + 3];
            float b0 = Bs[kk][tx * 4 + 0], b1 = Bs[kk][tx * 4 + 1];
            float b2 = Bs[kk][tx * 4 + 2], b3 = Bs[kk][tx * 4 + 3];
            acc[0][0] = fmaf(a0, b0, acc[0][0]); acc[0][1] = fmaf(a0, b1, acc[0][1]);
            acc[0][2] = fmaf(a0, b2, acc[0][2]); acc[0][3] = fmaf(a0, b3, acc[0][3]);
            acc[1][0] = fmaf(a1, b0, acc[1][0]); acc[1][1] = fmaf(a1, b1, acc[1][1]);
            acc[1][2] = fmaf(a1, b2, acc[1][2]); acc[1][3] = fmaf(a1, b3, acc[1][3]);
            acc[2][0] = fmaf(a2, b0, acc[2][0]); acc[2][1] = fmaf(a2, b1, acc[2][1]);
            acc[2][2] = fmaf(a2, b2, acc[2][2]); acc[2][3] = fmaf(a2, b3, acc[2][3]);
            acc[3][0] = fmaf(a3, b0, acc[3][0]); acc[3][1] = fmaf(a3, b1, acc[3][1]);
            acc[3][2] = fmaf(a3, b2, acc[3][2]); acc[3][3] = fmaf(a3, b3, acc[3][3]);
        }
        __syncthreads();
    }
#pragma unroll
    for (int r = 0; r < 4; r++) {
        int m = bm + ty * 4 + r;
#pragma unroll
        for (int c = 0; c < 4; c++) {
            int nn = bn + tx * 4 + c;
            float v = acc[r][c];
            if (bias) v += bias[nn];
            if (relu) v = fmaxf(v, 0.f);
            C[(size_t)m * N + nn] = v;
        }
    }
}

// ---------------- tpos = pos + h @ Wt + bt  (one wave per node) ----------------
__global__ __launch_bounds__(256) void k_tpos(const float* __restrict__ h,
        const float* __restrict__ Wt, const float* __restrict__ bt,
        const float* __restrict__ pos, float* __restrict__ tpos)
{
    int node = blockIdx.x * 4 + (threadIdx.x >> 6);
    int lane = threadIdx.x & 63;
    const float* hr = &h[(size_t)node * F_OUT];
    float v0 = hr[lane], v1 = hr[lane + 64];
    float s0 = v0 * Wt[lane * 3 + 0] + v1 * Wt[(lane + 64) * 3 + 0];
    float s1 = v0 * Wt[lane * 3 + 1] + v1 * Wt[(lane + 64) * 3 + 1];
    float s2 = v0 * Wt[lane * 3 + 2] + v1 * Wt[(lane + 64) * 3 + 2];
    for (int o = 32; o > 0; o >>= 1) {
        s0 += __shfl_down(s0, o);
        s1 += __shfl_down(s1, o);
        s2 += __shfl_down(s2, o);
    }
    if (lane == 0) {
        tpos[node * 3 + 0] = pos[node * 3 + 0] + s0 + bt[0];
        tpos[node * 3 + 1] = pos[node * 3 + 1] + s1 + bt[1];
        tpos[node * 3 + 2] = pos[node * 3 + 2] + s2 + bt[2];
    }
}

// ---------------- ICP ----------------
__global__ void k_icp_init(double* __restrict__ T) {
    int t = threadIdx.x;
    if (t < B_GRAPHS * 12) {
        int k = t % 12;
        T[t] = (k == 0 || k == 4 || k == 8) ? 1.0 : 0.0;
    }
}

// NN + correspondence-moment partial sums. One block: 64 src pts, each scanned by 4
// threads covering 512 tgt pts each. Cumulative transform T applied to original tpos.
__global__ __launch_bounds__(256) void k_icp_nn(const float* __restrict__ tpos,
        const float* __restrict__ pos, const double* __restrict__ T,
        float* __restrict__ partials)
{
    const int g   = blockIdx.x >> 5;
    const int blk = blockIdx.x & 31;
    __shared__ float4 tq4s[NPG_];
    __shared__ float  Tf[12];
    __shared__ float  redd[256];
    __shared__ int    redi[256];
    float* tq = (float*)tq4s;
    const int tid = threadIdx.x;
    for (int i = tid; i < NPG_; i += 256) {
        const float* p = &pos[(size_t)(g * NPG_ + i) * 3];
        tq[i * 4 + 0] = p[0]; tq[i * 4 + 1] = p[1]; tq[i * 4 + 2] = p[2]; tq[i * 4 + 3] = 0.f;
    }
    if (tid < 12) Tf[tid] = (float)T[g * 12 + tid];
    __syncthreads();
    const int sp = tid & 63;
    const int qt = tid >> 6;
    const int n  = g * NPG_ + blk * 64 + sp;
    float px = tpos[n * 3 + 0], py = tpos[n * 3 + 1], pz = tpos[n * 3 + 2];
    float X = Tf[0] * px + Tf[1] * py + Tf[2] * pz + Tf[9];
    float Y = Tf[3] * px + Tf[4] * py + Tf[5] * pz + Tf[10];
    float Z = Tf[6] * px + Tf[7] * py + Tf[8] * pz + Tf[11];
    const int j0 = qt * 512;
    const float4* tq4 = tq4s;
    float b0 = 1e30f, b1 = 1e30f, b2 = 1e30f, b3 = 1e30f;
    int   i0 = j0, i1 = j0 + 1, i2 = j0 + 2, i3 = j0 + 3;
    for (int j = 0; j < 512; j += 4) {
        float4 q0 = tq4[j0 + j + 0];
        float4 q1 = tq4[j0 + j + 1];
        float4 q2 = tq4[j0 + j + 2];
        float4 q3 = tq4[j0 + j + 3];
        float dx, dy, dz, d;
        dx = X - q0.x; dy = Y - q0.y; dz = Z - q0.z; d = fmaf(dx, dx, fmaf(dy, dy, dz * dz));
        if (d < b0) { b0 = d; i0 = j0 + j + 0; }
        dx = X - q1.x; dy = Y - q1.y; dz = Z - q1.z; d = fmaf(dx, dx, fmaf(dy, dy, dz * dz));
        if (d < b1) { b1 = d; i1 = j0 + j + 1; }
        dx = X - q2.x; dy = Y - q2.y; dz = Z - q2.z; d = fmaf(dx, dx, fmaf(dy, dy, dz * dz));
        if (d < b2) { b2 = d; i2 = j0 + j + 2; }
        dx = X - q3.x; dy = Y - q3.y; dz = Z - q3.z; d = fmaf(dx, dx, fmaf(dy, dy, dz * dz));
        if (d < b3) { b3 = d; i3 = j0 + j + 3; }
    }
    // combine 4 interleaved streams; ties -> smaller index (argmin first-occurrence)
    float bb = b0; int ib = i0;
    if (b1 < bb || (b1 == bb && i1 < ib)) { bb = b1; ib = i1; }
    if (b2 < bb || (b2 == bb && i2 < ib)) { bb = b2; ib = i2; }
    if (b3 < bb || (b3 == bb && i3 < ib)) { bb = b3; ib = i3; }
    redd[tid] = bb; redi[tid] = ib;
    __syncthreads();
    if (tid < 64) {
        float best = redd[tid]; int bi = redi[tid];
#pragma unroll
        for (int r = 1; r < 4; r++) {  // quarter index ranges ascend -> strict < keeps min idx
            float dd = redd[tid + 64 * r]; int ii = redi[tid + 64 * r];
            if (dd < best) { best = dd; bi = ii; }
        }
        float qx = tq[bi * 4 + 0], qy = tq[bi * 4 + 1], qz = tq[bi * 4 + 2];
        float vals[15] = { X, Y, Z, qx, qy, qz,
                           X * qx, X * qy, X * qz,
                           Y * qx, Y * qy, Y * qz,
                           Z * qx, Z * qy, Z * qz };
#pragma unroll
        for (int k = 0; k < 15; k++) {
            float v = vals[k];
            for (int o = 32; o > 0; o >>= 1) v += __shfl_down(v, o);
            if (tid == 0) partials[blockIdx.x * 15 + k] = v;
        }
    }
}

// Per-graph 3x3 Kabsch (fp64 Jacobi SVD) + cumulative transform update. 8 lanes active.
__global__ void k_icp_svd(const float* __restrict__ partials, double* __restrict__ T)
{
    int g = threadIdx.x;
    if (g >= B_GRAPHS) return;
    double s[15];
#pragma unroll
    for (int k = 0; k < 15; k++) {
        double acc = 0;
        for (int b = 0; b < NN_BPG; b++) acc += (double)partials[(g * NN_BPG + b) * 15 + k];
        s[k] = acc;
    }
    const double n = (double)NPG_;
    double cs0 = s[0] / n, cs1 = s[1] / n, cs2 = s[2] / n;
    double cc0 = s[3] / n, cc1 = s[4] / n, cc2 = s[5] / n;
    double H[3][3];
    H[0][0] = s[6]  - n * cs0 * cc0; H[0][1] = s[7]  - n * cs0 * cc1; H[0][2] = s[8]  - n * cs0 * cc2;
    H[1][0] = s[9]  - n * cs1 * cc0; H[1][1] = s[10] - n * cs1 * cc1; H[1][2] = s[11] - n * cs1 * cc2;
    H[2][0] = s[12] - n * cs2 * cc0; H[2][1] = s[13] - n * cs2 * cc1; H[2][2] = s[14] - n * cs2 * cc2;

    // Jacobi eigen of A = H^T H
    double A[3][3];
    for (int i = 0; i < 3; i++)
        for (int j = 0; j < 3; j++)
            A[i][j] = H[0][i] * H[0][j] + H[1][i] * H[1][j] + H[2][i] * H[2][j];
    double V[3][3] = {{1,0,0},{0,1,0},{0,0,1}};
    for (int sweep = 0; sweep < 25; ++sweep) {
        double off = A[0][1]*A[0][1] + A[0][2]*A[0][2] + A[1][2]*A[1][2];
        if (off < 1e-28) break;
        for (int p = 0; p < 2; p++) for (int q = p + 1; q < 3; q++) {
            double apq = A[p][q];
            if (apq == 0.0) continue;
            double theta = (A[q][q] - A[p][p]) / (2.0 * apq);
            double tt = copysign(1.0, theta) / (fabs(theta) + sqrt(theta * theta + 1.0));
            double cj = 1.0 / sqrt(tt * tt + 1.0);
            double sj = tt * cj;
            for (int k = 0; k < 3; k++) { double akp = A[k][p], akq = A[k][q]; A[k][p] = cj*akp - sj*akq; A[k][q] = sj*akp + cj*akq; }
            for (int k = 0; k < 3; k++) { double apk = A[p][k], aqk = A[q][k]; A[p][k] = cj*apk - sj*aqk; A[q][k] = sj*apk + cj*aqk; }
            for (int k = 0; k < 3; k++) { double vkp = V[k][p], vkq = V[k][q]; V[k][p] = cj*vkp - sj*vkq; V[k][q] = sj*vkp + cj*vkq; }
        }
    }
    double lam[3] = { A[0][0], A[1][1], A[2][2] };
    int ord[3] = { 0, 1, 2 };
    if (lam[ord[1]] > lam[ord[0]]) { int t0 = ord[0]; ord[0] = ord[1]; ord[1] = t0; }
    if (lam[ord[2]] > lam[ord[0]]) { int t0 = ord[0]; ord[0] = ord[2]; ord[2] = t0; }
    if (lam[ord[2]] > lam[ord[1]]) { int t0 = ord[1]; ord[1] = ord[2]; ord[2] = t0; }
    double vc[3][3], uc[3][3];
    for (int i = 0; i < 3; i++) { vc[i][0] = V[0][ord[i]]; vc[i][1] = V[1][ord[i]]; vc[i][2] = V[2][ord[i]]; }
    for (int i = 0; i < 3; i++) {
        double u0 = H[0][0]*vc[i][0] + H[0][1]*vc[i][1] + H[0][2]*vc[i][2];
        double u1 = H[1][0]*vc[i][0] + H[1][1]*vc[i][1] + H[1][2]*vc[i][2];
        double u2 = H[2][0]*vc[i][0] + H[2][1]*vc[i][1] + H[2][2]*vc[i][2];
        for (int j = 0; j < i; j++) {
            double dp = u0*uc[j][0] + u1*uc[j][1] + u2*uc[j][2];
            u0 -= dp*uc[j][0]; u1 -= dp*uc[j][1]; u2 -= dp*uc[j][2];
        }
        double nn2 = sqrt(u0*u0 + u1*u1 + u2*u2);
        if (nn2 > 1e-20) { uc[i][0] = u0/nn2; uc[i][1] = u1/nn2; uc[i][2] = u2/nn2; }
        else if (i == 2) {
            uc[2][0] = uc[0][1]*uc[1][2] - uc[0][2]*uc[1][1];
            uc[2][1] = uc[0][2]*uc[1][0] - uc[0][0]*uc[1][2];
            uc[2][2] = uc[0][0]*uc[1][1] - uc[0][1]*uc[1][0];
        } else if (i == 1) {
            double a0 = (fabs(uc[0][0]) < 0.9) ? 1.0 : 0.0, a1 = 1.0 - a0, a2 = 0.0;
            double dp = a0*uc[0][0] + a1*uc[0][1] + a2*uc[0][2];
            a0 -= dp*uc[0][0]; a1 -= dp*uc[0][1]; a2 -= dp*uc[0][2];
            double nn3 = sqrt(a0*a0 + a1*a1 + a2*a2);
            uc[1][0] = a0/nn3; uc[1][1] = a1/nn3; uc[1][2] = a2/nn3;
        } else { uc[0][0] = 1; uc[0][1] = 0; uc[0][2] = 0; }
    }
    double detU = uc[0][0]*(uc[1][1]*uc[2][2] - uc[1][2]*uc[2][1])
                - uc[0][1]*(uc[1][0]*uc[2][2] - uc[1][2]*uc[2][0])
                + uc[0][2]*(uc[1][0]*uc[2][1] - uc[1][1]*uc[2][0]);
    // note: rows of uc are columns of U -> det(U) = det(uc^T) = det(uc)
    double detV = vc[0][0]*(vc[1][1]*vc[2][2] - vc[1][2]*vc[2][1])
                - vc[0][1]*(vc[1][0]*vc[2][2] - vc[1][2]*vc[2][0])
                + vc[0][2]*(vc[1][0]*vc[2][1] - vc[1][1]*vc[2][0]);
    double sgn = (detU * detV < 0.0) ? -1.0 : 1.0;
    double R[3][3];
    for (int i = 0; i < 3; i++)
        for (int j = 0; j < 3; j++)
            R[i][j] = vc[0][i]*uc[0][j] + vc[1][i]*uc[1][j] + sgn * vc[2][i]*uc[2][j];
    double tr0 = cc0 - (R[0][0]*cs0 + R[0][1]*cs1 + R[0][2]*cs2);
    double tr1 = cc1 - (R[1][0]*cs0 + R[1][1]*cs1 + R[1][2]*cs2);
    double tr2 = cc2 - (R[2][0]*cs0 + R[2][1]*cs1 + R[2][2]*cs2);
    double Ao[12];
#pragma unroll
    for (int k = 0; k < 12; k++) Ao[k] = T[g * 12 + k];
    double An[12];
    for (int i = 0; i < 3; i++)
        for (int j = 0; j < 3; j++)
            An[i*3+j] = R[i][0]*Ao[0*3+j] + R[i][1]*Ao[1*3+j] + R[i][2]*Ao[2*3+j];
    An[9]  = R[0][0]*Ao[9] + R[0][1]*Ao[10] + R[0][2]*Ao[11] + tr0;
    An[10] = R[1][0]*Ao[9] + R[1][1]*Ao[10] + R[1][2]*Ao[11] + tr1;
    An[11] = R[2][0]*Ao[9] + R[2][1]*Ao[10] + R[2][2]*Ao[11] + tr2;
#pragma unroll
    for (int k = 0; k < 12; k++) T[g * 12 + k] = An[k];
}

__global__ void k_icp_apply(const float* __restrict__ tpos, const double* __restrict__ T,
                            float* __restrict__ out)
{
    int n = blockIdx.x * 256 + threadIdx.x;
    if (n >= N_NODES) return;
    int g = n >> 11;
    const double* Tg = &T[g * 12];
    double px = tpos[n*3+0], py = tpos[n*3+1], pz = tpos[n*3+2];
    out[n*3+0] = (float)(Tg[0]*px + Tg[1]*py + Tg[2]*pz + Tg[9]);
    out[n*3+1] = (float)(Tg[3]*px + Tg[4]*py + Tg[5]*pz + Tg[10]);
    out[n*3+2] = (float)(Tg[6]*px + Tg[7]*py + Tg[8]*pz + Tg[11]);
}

// ---------------- chamfer: per-A-point min dist to B, summed per block ----------------
__global__ __launch_bounds__(256) void k_chamfer(const float* __restrict__ Apts,
        const float* __restrict__ Bpts, float* __restrict__ part)
{
    const int g = blockIdx.x >> 5, blk = blockIdx.x & 31;
    __shared__ float4 bq4s[NPG_];
    __shared__ float  redd[256];
    float* bq = (float*)bq4s;
    const int tid = threadIdx.x;
    for (int i = tid; i < NPG_; i += 256) {
        const float* p = &Bpts[(size_t)(g * NPG_ + i) * 3];
        bq[i*4+0] = p[0]; bq[i*4+1] = p[1]; bq[i*4+2] = p[2]; bq[i*4+3] = 0.f;
    }
    __syncthreads();
    const int sp = tid & 63, qt = tid >> 6;
    const int n = g * NPG_ + blk * 64 + sp;
    float X = Apts[n*3+0], Y = Apts[n*3+1], Z = Apts[n*3+2];
    const int j0 = qt * 512;
    float b0 = 1e30f, b1 = 1e30f, b2 = 1e30f, b3 = 1e30f;
    for (int j = 0; j < 512; j += 4) {
        float4 q0 = bq4s[j0+j+0], q1 = bq4s[j0+j+1], q2 = bq4s[j0+j+2], q3 = bq4s[j0+j+3];
        float dx, dy, dz;
        dx = X - q0.x; dy = Y - q0.y; dz = Z - q0.z; b0 = fminf(b0, fmaf(dx, dx, fmaf(dy, dy, dz*dz)));
        dx = X - q1.x; dy = Y - q1.y; dz = Z - q1.z; b1 = fminf(b1, fmaf(dx, dx, fmaf(dy, dy, dz*dz)));
        dx = X - q2.x; dy = Y - q2.y; dz = Z - q2.z; b2 = fminf(b2, fmaf(dx, dx, fmaf(dy, dy, dz*dz)));
        dx = X - q3.x; dy = Y - q3.y; dz = Z - q3.z; b3 = fminf(b3, fmaf(dx, dx, fmaf(dy, dy, dz*dz)));
    }
    redd[tid] = fminf(fminf(b0, b1), fminf(b2, b3));
    __syncthreads();
    if (tid < 64) {
        float v = redd[tid];
        v = fminf(v, redd[tid + 64]);
        v = fminf(v, redd[tid + 128]);
        v = fminf(v, redd[tid + 192]);
        for (int o = 32; o > 0; o >>= 1) v += __shfl_down(v, o);
        if (tid == 0) part[blockIdx.x] = v;
    }
}

__global__ void k_loss(const float* __restrict__ pA, const float* __restrict__ pB,
                       float* __restrict__ out)
{
    if (threadIdx.x == 0 && blockIdx.x == 0) {
        double acc = 0;
        for (int g = 0; g < B_GRAPHS; ++g) {
            double s1 = 0, s2 = 0;
            for (int b = 0; b < NN_BPG; b++) { s1 += pA[g*NN_BPG + b]; s2 += pB[g*NN_BPG + b]; }
            acc += s1 / (double)NPG_ + s2 / (double)NPG_;
        }
        out[0] = (float)(acc / (double)B_GRAPHS);
    }
}

// ---------------- launcher ----------------
extern "C" void kernel_launch(void* const* d_in, const int* in_sizes, int n_in,
                              void* d_out, int out_size, void* d_ws, size_t ws_size,
                              hipStream_t stream)
{
    (void)in_sizes; (void)n_in; (void)out_size; (void)ws_size;
    const float* x   = (const float*)d_in[0];
    const int*   ei  = (const int*)d_in[1];
    const float* pos = (const float*)d_in[2];
    const float* W1 = (const float*)d_in[4];
    const float* b1 = (const float*)d_in[5];
    const float* W2 = (const float*)d_in[6];
    const float* b2 = (const float*)d_in[7];
    const float* W3 = (const float*)d_in[8];
    const float* b3 = (const float*)d_in[9];
    const float* Wt = (const float*)d_in[10];
    const float* bt = (const float*)d_in[11];
    const int* row = ei;
    const int* col = ei + E_EDGES;

    char* wsb = (char*)d_ws;
    size_t off_b = 0;
    auto alloc = [&](size_t bytes) -> void* {
        void* p = wsb + off_b;
        off_b = (off_b + bytes + 255) & ~(size_t)255;
        return p;
    };
    int*    counts   = (int*)alloc((size_t)N_NODES * 4);
    int*    offs     = (int*)alloc((size_t)(N_NODES + 1) * 4);
    int*    cursor   = (int*)alloc((size_t)N_NODES * 4);
    int*    srcid    = (int*)alloc((size_t)E_EDGES * 4);
    float*  normv    = (float*)alloc((size_t)E_EDGES * 4);
    float*  dinv     = (float*)alloc((size_t)N_NODES * 4);
    float*  buf1     = (float*)alloc((size_t)N_NODES * F_HID * 4);
    float*  buf2     = (float*)alloc((size_t)N_NODES * F_HID * 4);
    float*  tpos     = (float*)alloc((size_t)N_NODES * 3 * 4);
    double* T        = (double*)alloc((size_t)B_GRAPHS * 12 * 8);
    float*  partials = (float*)alloc((size_t)B_GRAPHS * NN_BPG * 15 * 4);
    float*  chA      = (float*)alloc((size_t)B_GRAPHS * NN_BPG * 4);
    float*  chB      = (float*)alloc((size_t)B_GRAPHS * NN_BPG * 4);

    float* out_h       = (float*)d_out;
    float* out_aligned = out_h + (size_t)N_NODES * F_OUT;
    float* out_loss    = out_aligned + (size_t)N_NODES * 3;

    // CSR build
    hipMemsetAsync(counts, 0, (size_t)N_NODES * 4, stream);
    k_count<<<E_EDGES / 256, 256, 0, stream>>>(col, counts);
    k_scan<<<1, 1024, 0, stream>>>(counts, offs, cursor, dinv);
    k_scatter<<<E_EDGES / 256, 256, 0, stream>>>(row, col, cursor, dinv, srcid, normv);

    // GCN layer 1: (A_hat x) @ W1 + b1, relu
    k_aggregate<F_IN><<<N_NODES, F_IN, 0, stream>>>(x, buf1, offs, srcid, normv, dinv, nullptr, 0);
    dim3 g256(F_HID / 64, N_NODES / 64);
    k_gemm<<<g256, 256, 0, stream>>>(buf1, W1, b1, buf2, N_NODES, F_HID, F_IN, 1);
    // GCN layer 2: A_hat (h1 @ W2) + b2, relu
    k_gemm<<<g256, 256, 0, stream>>>(buf2, W2, nullptr, buf1, N_NODES, F_HID, F_HID, 0);
    k_aggregate<F_HID><<<N_NODES, F_HID, 0, stream>>>(buf1, buf2, offs, srcid, normv, dinv, b2, 1);
    // GCN layer 3: A_hat (h2 @ W3) + b3  -> h output
    dim3 g128(F_OUT / 64, N_NODES / 64);
    k_gemm<<<g128, 256, 0, stream>>>(buf2, W3, nullptr, buf1, N_NODES, F_OUT, F_HID, 0);
    k_aggregate<F_OUT><<<N_NODES, F_OUT, 0, stream>>>(buf1, out_h, offs, srcid, normv, dinv, b3, 0);

    // tpos = pos + h @ Wt + bt
    k_tpos<<<N_NODES / 4, 256, 0, stream>>>(out_h, Wt, bt, pos, tpos);

    // ICP (cumulative transform per graph)
    k_icp_init<<<1, 128, 0, stream>>>(T);
    for (int it = 0; it < ICP_IT; ++it) {
        k_icp_nn<<<B_GRAPHS * NN_BPG, 256, 0, stream>>>(tpos, pos, T, partials);
        k_icp_svd<<<1, 64, 0, stream>>>(partials, T);
    }
    k_icp_apply<<<N_NODES / 256, 256, 0, stream>>>(tpos, T, out_aligned);

    // chamfer + loss
    k_chamfer<<<B_GRAPHS * NN_BPG, 256, 0, stream>>>(out_aligned, pos, chA);
    k_chamfer<<<B_GRAPHS * NN_BPG, 256, 0, stream>>>(pos, out_aligned, chB);
    k_loss<<<1, 64, 0, stream>>>(chA, chB, out_loss);
}

// Round 2
// 466.474 us; speedup vs baseline: 1.4990x; 1.4990x over previous
//
#include <hip/hip_runtime.h>
#include <math.h>

#define N_NODES 16384
#define B_GRAPHS 8
#define NPG_     2048
#define E_EDGES  262144
#define F_IN  128
#define F_HID 256
#define F_OUT 128
#define ICP_IT 10
#define NN_BPG 32   // blocks per graph in NN-style kernels (64 src pts/block)

typedef __attribute__((ext_vector_type(8))) short bf16x8;
typedef __attribute__((ext_vector_type(4))) float f32x4;

__device__ __forceinline__ float b2f(unsigned short u) {
    union { unsigned int u; float f; } v; v.u = ((unsigned int)u) << 16; return v.f;
}
__device__ __forceinline__ unsigned short f2b(float f) {
    union { float f; unsigned int u; } v; v.f = f;
    unsigned int r = v.u + 0x7FFFu + ((v.u >> 16) & 1u);
    return (unsigned short)(r >> 16);
}

// ---------------- fp32 -> bf16 convert (vectorized) ----------------
__global__ void k_f2b(const float* __restrict__ in, unsigned short* __restrict__ out, int n4) {
    int i = blockIdx.x * 256 + threadIdx.x;
    if (i >= n4) return;
    float4 v = ((const float4*)in)[i];
    uint2 o;
    o.x = (unsigned int)f2b(v.x) | ((unsigned int)f2b(v.y) << 16);
    o.y = (unsigned int)f2b(v.z) | ((unsigned int)f2b(v.w) << 16);
    ((uint2*)out)[i] = o;
}

// ---------------- weight transpose-convert: W[K][N] fp32 -> Wb[N][K] bf16 ----------------
__global__ void k_wconv(const float* __restrict__ W, unsigned short* __restrict__ Wb,
                        int K, int N, int lgN) {
    int idx = blockIdx.x * 256 + threadIdx.x;
    if (idx >= K * N) return;
    int k = idx >> lgN, n = idx & (N - 1);
    Wb[(size_t)n * K + k] = f2b(W[idx]);
}

// ---------------- CSR build ----------------
__global__ void k_count(const int* __restrict__ col, int* __restrict__ counts) {
    int e = blockIdx.x * 256 + threadIdx.x;
    if (e < E_EDGES) atomicAdd(&counts[col[e]], 1);
}

__global__ __launch_bounds__(1024) void k_scan(const int* __restrict__ counts,
        int* __restrict__ offs, int* __restrict__ cursor, float* __restrict__ dinv)
{
    __shared__ int sums[1024];
    const int t = threadIdx.x;
    const int base = t * 16;
    int local[16];
    int s = 0;
#pragma unroll
    for (int i = 0; i < 16; i++) { local[i] = counts[base + i]; s += local[i]; }
    sums[t] = s;
    __syncthreads();
    for (int o = 1; o < 1024; o <<= 1) {
        int v = 0;
        if (t >= o) v = sums[t - o];
        __syncthreads();
        sums[t] += v;
        __syncthreads();
    }
    int run = (t == 0) ? 0 : sums[t - 1];
#pragma unroll
    for (int i = 0; i < 16; i++) {
        offs[base + i]   = run;
        cursor[base + i] = run;
        dinv[base + i]   = rsqrtf((float)(local[i] + 1));  // deg = indeg + self loop
        run += local[i];
    }
    if (t == 1023) offs[N_NODES] = run;
}

__global__ void k_scatter(const int* __restrict__ row, const int* __restrict__ col,
        int* __restrict__ cursor, const float* __restrict__ dinv,
        int* __restrict__ srcid, float* __restrict__ normv)
{
    int e = blockIdx.x * 256 + threadIdx.x;
    if (e >= E_EDGES) return;
    int r = row[e], c = col[e];
    int p = atomicAdd(&cursor[c], 1);
    srcid[p] = r;
    normv[p] = dinv[r] * dinv[c];
}

// ---------------- GCN aggregation (bf16 in, fp32 acc) ----------------
template<int W, int OUTF>
__global__ void k_agg(const unsigned short* __restrict__ X, void* __restrict__ Y,
        const int* __restrict__ offs, const int* __restrict__ srcid,
        const float* __restrict__ normv, const float* __restrict__ dinv,
        const float* __restrict__ bias, int relu)
{
    const int n = blockIdx.x;
    const int j = threadIdx.x;
    const unsigned int* Xu = (const unsigned int*)X;
    const int W2 = W / 2;
    float di = dinv[n];
    float w0 = di * di;
    unsigned int v = Xu[(size_t)n * W2 + j];
    float a0 = b2f((unsigned short)v) * w0;
    float a1 = b2f((unsigned short)(v >> 16)) * w0;
    int p = offs[n];
    const int p1 = offs[n + 1];
    for (; p + 1 < p1; p += 2) {
        unsigned int va = Xu[(size_t)srcid[p] * W2 + j];     float na = normv[p];
        unsigned int vb = Xu[(size_t)srcid[p + 1] * W2 + j]; float nb = normv[p + 1];
        a0 = fmaf(b2f((unsigned short)va), na, a0);
        a1 = fmaf(b2f((unsigned short)(va >> 16)), na, a1);
        a0 = fmaf(b2f((unsigned short)vb), nb, a0);
        a1 = fmaf(b2f((unsigned short)(vb >> 16)), nb, a1);
    }
    if (p < p1) {
        unsigned int va = Xu[(size_t)srcid[p] * W2 + j]; float na = normv[p];
        a0 = fmaf(b2f((unsigned short)va), na, a0);
        a1 = fmaf(b2f((unsigned short)(va >> 16)), na, a1);
    }
    if (bias) { a0 += bias[2 * j]; a1 += bias[2 * j + 1]; }
    if (relu) { a0 = fmaxf(a0, 0.f); a1 = fmaxf(a1, 0.f); }
    if (OUTF) {
        float* Yf = (float*)Y;
        Yf[(size_t)n * W + 2 * j]     = a0;
        Yf[(size_t)n * W + 2 * j + 1] = a1;
    } else {
        ((unsigned int*)Y)[(size_t)n * W2 + j] =
            (unsigned int)f2b(a0) | ((unsigned int)f2b(a1) << 16);
    }
}

// ---------------- bf16 MFMA GEMM: C[M,N] = A[M,K] @ Bt[N,K]^T (+bias,relu) ----------------
__global__ __launch_bounds__(256) void k_gemm_bf16(
    const unsigned short* __restrict__ A,   // [M][K] bf16
    const unsigned short* __restrict__ Bt,  // [N][K] bf16
    const float* __restrict__ bias, unsigned short* __restrict__ C,
    int M, int N, int K, int relu)
{
    __shared__ __align__(16) unsigned short As[128 * 64];  // 16KB, rows of 128B (8 slots)
    __shared__ __align__(16) unsigned short Bs[64 * 64];   // 8KB
    const int tid  = threadIdx.x;
    const int lane = tid & 63;
    const int wave = tid >> 6;
    const int bm = blockIdx.y * 128, bn = blockIdx.x * 64;
    const int wm = (wave >> 1) * 64, wn = (wave & 1) * 32;
    f32x4 acc[4][2];
#pragma unroll
    for (int mf = 0; mf < 4; mf++)
#pragma unroll
        for (int nf = 0; nf < 2; nf++) acc[mf][nf] = (f32x4){0.f, 0.f, 0.f, 0.f};

    for (int k0 = 0; k0 < K; k0 += 64) {
#pragma unroll
        for (int i = 0; i < 4; i++) {   // A: 128 rows x 8 slots of 16B
            int idx = i * 256 + tid;
            int m = idx >> 3, slot = idx & 7;
            const unsigned short* src = A + (size_t)(bm + m) * K + k0 + ((slot ^ (m & 7)) << 3);
            __builtin_amdgcn_global_load_lds(
                (const __attribute__((address_space(1))) unsigned int*)src,
                (__attribute__((address_space(3))) unsigned int*)(As + (size_t)i * 2048 + wave * 512),
                16, 0, 0);
        }
#pragma unroll
        for (int i = 0; i < 2; i++) {   // B: 64 rows x 8 slots
            int idx = i * 256 + tid;
            int n = idx >> 3, slot = idx & 7;
            const unsigned short* src = Bt + (size_t)(bn + n) * K + k0 + ((slot ^ (n & 7)) << 3);
            __builtin_amdgcn_global_load_lds(
                (const __attribute__((address_space(1))) unsigned int*)src,
                (__attribute__((address_space(3))) unsigned int*)(Bs + (size_t)i * 2048 + wave * 512),
                16, 0, 0);
        }
        __syncthreads();
        bf16x8 af[4][2], bfr[2][2];
        const int qd = lane >> 4;
#pragma unroll
        for (int s = 0; s < 2; s++) {
#pragma unroll
            for (int mf = 0; mf < 4; mf++) {
                int m = wm + mf * 16 + (lane & 15);
                int slot = (s * 4 + qd) ^ (m & 7);
                af[mf][s] = *(const bf16x8*)(As + m * 64 + slot * 8);
            }
#pragma unroll
            for (int nf = 0; nf < 2; nf++) {
                int n = wn + nf * 16 + (lane & 15);
                int slot = (s * 4 + qd) ^ (n & 7);
                bfr[nf][s] = *(const bf16x8*)(Bs + n * 64 + slot * 8);
            }
        }
#pragma unroll
        for (int s = 0; s < 2; s++)
#pragma unroll
            for (int mf = 0; mf < 4; mf++)
#pragma unroll
                for (int nf = 0; nf < 2; nf++)
                    acc[mf][nf] = __builtin_amdgcn_mfma_f32_16x16x32_bf16(
                        af[mf][s], bfr[nf][s], acc[mf][nf], 0, 0, 0);
        __syncthreads();
    }
#pragma unroll
    for (int nf = 0; nf < 2; nf++) {
        int col = bn + wn + nf * 16 + (lane & 15);
        float bv = bias ? bias[col] : 0.f;
#pragma unroll
        for (int mf = 0; mf < 4; mf++) {
#pragma unroll
            for (int r = 0; r < 4; r++) {
                int row = bm + wm + mf * 16 + (lane >> 4) * 4 + r;
                float v = acc[mf][nf][r] + bv;
                if (relu) v = fmaxf(v, 0.f);
                C[(size_t)row * N + col] = f2b(v);
            }
        }
    }
}

// ---------------- tpos = pos + h @ Wt + bt ----------------
__global__ __launch_bounds__(256) void k_tpos(const float* __restrict__ h,
        const float* __restrict__ Wt, const float* __restrict__ bt,
        const float* __restrict__ pos, float* __restrict__ tpos)
{
    int node = blockIdx.x * 4 + (threadIdx.x >> 6);
    int lane = threadIdx.x & 63;
    const float* hr = &h[(size_t)node * F_OUT];
    float v0 = hr[lane], v1 = hr[lane + 64];
    float s0 = v0 * Wt[lane * 3 + 0] + v1 * Wt[(lane + 64) * 3 + 0];
    float s1 = v0 * Wt[lane * 3 + 1] + v1 * Wt[(lane + 64) * 3 + 1];
    float s2 = v0 * Wt[lane * 3 + 2] + v1 * Wt[(lane + 64) * 3 + 2];
    for (int o = 32; o > 0; o >>= 1) {
        s0 += __shfl_down(s0, o);
        s1 += __shfl_down(s1, o);
        s2 += __shfl_down(s2, o);
    }
    if (lane == 0) {
        tpos[node * 3 + 0] = pos[node * 3 + 0] + s0 + bt[0];
        tpos[node * 3 + 1] = pos[node * 3 + 1] + s1 + bt[1];
        tpos[node * 3 + 2] = pos[node * 3 + 2] + s2 + bt[2];
    }
}

// ---------------- ICP ----------------
__global__ void k_icp_init(double* __restrict__ T) {
    int t = threadIdx.x;
    if (t < B_GRAPHS * 12) {
        int k = t % 12;
        T[t] = (k == 0 || k == 4 || k == 8) ? 1.0 : 0.0;
    }
}

__global__ __launch_bounds__(512) void k_icp_nn(const float* __restrict__ tpos,
        const float* __restrict__ pos, const double* __restrict__ T,
        float* __restrict__ partials)
{
    const int g = blockIdx.x >> 5, blk = blockIdx.x & 31;
    __shared__ float4 tq4s[NPG_];
    __shared__ float Tf[12];
    __shared__ float redd[64 * 65];
    __shared__ unsigned short redi[64 * 65];
    const int tid = threadIdx.x;
    for (int i = tid; i < NPG_; i += 512) {
        const float* p = &pos[(size_t)(g * NPG_ + i) * 3];
        tq4s[i] = make_float4(p[0], p[1], p[2], 0.f);
    }
    if (tid < 12) Tf[tid] = (float)T[g * 12 + tid];
    __syncthreads();
    const int sg = tid & 7;
    const int q  = tid >> 3;
    const int j0 = q * 32;
    float Xs[8], Ys[8], Zs[8], bd[8];
    int bi[8];
#pragma unroll
    for (int u = 0; u < 8; u++) {
        int n = g * NPG_ + blk * 64 + sg * 8 + u;
        float px = tpos[n * 3 + 0], py = tpos[n * 3 + 1], pz = tpos[n * 3 + 2];
        Xs[u] = Tf[0] * px + Tf[1] * py + Tf[2] * pz + Tf[9];
        Ys[u] = Tf[3] * px + Tf[4] * py + Tf[5] * pz + Tf[10];
        Zs[u] = Tf[6] * px + Tf[7] * py + Tf[8] * pz + Tf[11];
        bd[u] = 1e30f; bi[u] = j0;
    }
    for (int j = 0; j < 32; j++) {
        float4 t4 = tq4s[j0 + j];
#pragma unroll
        for (int u = 0; u < 8; u++) {
            float dx = Xs[u] - t4.x, dy = Ys[u] - t4.y, dz = Zs[u] - t4.z;
            float d = fmaf(dx, dx, fmaf(dy, dy, dz * dz));
            if (d < bd[u]) { bd[u] = d; bi[u] = j0 + j; }
        }
    }
#pragma unroll
    for (int u = 0; u < 8; u++) {
        redd[(sg * 8 + u) * 65 + q] = bd[u];
        redi[(sg * 8 + u) * 65 + q] = (unsigned short)bi[u];
    }
    __syncthreads();
    if (tid < 64) {
        float best = redd[tid * 65];
        int ib = redi[tid * 65];
        for (int r = 1; r < 64; r++) {
            float dd = redd[tid * 65 + r];
            if (dd < best) { best = dd; ib = redi[tid * 65 + r]; }
        }
        float4 c4 = tq4s[ib];
        int n = g * NPG_ + blk * 64 + tid;
        float px = tpos[n * 3 + 0], py = tpos[n * 3 + 1], pz = tpos[n * 3 + 2];
        float X = Tf[0] * px + Tf[1] * py + Tf[2] * pz + Tf[9];
        float Y = Tf[3] * px + Tf[4] * py + Tf[5] * pz + Tf[10];
        float Z = Tf[6] * px + Tf[7] * py + Tf[8] * pz + Tf[11];
        float vals[15] = { X, Y, Z, c4.x, c4.y, c4.z,
                           X * c4.x, X * c4.y, X * c4.z,
                           Y * c4.x, Y * c4.y, Y * c4.z,
                           Z * c4.x, Z * c4.y, Z * c4.z };
#pragma unroll
        for (int k = 0; k < 15; k++) {
            float v = vals[k];
            for (int o = 32; o > 0; o >>= 1) v += __shfl_down(v, o);
            if (tid == 0) partials[blockIdx.x * 15 + k] = v;
        }
    }
}

__global__ void k_icp_svd(const float* __restrict__ partials, double* __restrict__ T)
{
    int g = threadIdx.x;
    if (g >= B_GRAPHS) return;
    double sd[15];
#pragma unroll
    for (int k = 0; k < 15; k++) {
        double acc = 0;
        for (int b = 0; b < NN_BPG; b++) acc += (double)partials[(g * NN_BPG + b) * 15 + k];
        sd[k] = acc;
    }
    const double n = (double)NPG_;
    double cs0 = sd[0] / n, cs1 = sd[1] / n, cs2 = sd[2] / n;
    double cc0 = sd[3] / n, cc1 = sd[4] / n, cc2 = sd[5] / n;
    float H[3][3];
    H[0][0] = (float)(sd[6]  - n * cs0 * cc0); H[0][1] = (float)(sd[7]  - n * cs0 * cc1); H[0][2] = (float)(sd[8]  - n * cs0 * cc2);
    H[1][0] = (float)(sd[9]  - n * cs1 * cc0); H[1][1] = (float)(sd[10] - n * cs1 * cc1); H[1][2] = (float)(sd[11] - n * cs1 * cc2);
    H[2][0] = (float)(sd[12] - n * cs2 * cc0); H[2][1] = (float)(sd[13] - n * cs2 * cc1); H[2][2] = (float)(sd[14] - n * cs2 * cc2);

    float A[3][3], V[3][3] = {{1,0,0},{0,1,0},{0,0,1}};
    for (int i = 0; i < 3; i++)
        for (int j = 0; j < 3; j++)
            A[i][j] = H[0][i] * H[0][j] + H[1][i] * H[1][j] + H[2][i] * H[2][j];
    for (int sweep = 0; sweep < 8; ++sweep) {
        for (int p = 0; p < 2; p++) for (int q = p + 1; q < 3; q++) {
            float apq = A[p][q];
            if (fabsf(apq) < 1e-30f) continue;
            float theta = (A[q][q] - A[p][p]) / (2.f * apq);
            float t = copysignf(1.f, theta) / (fabsf(theta) + sqrtf(theta * theta + 1.f));
            float c = 1.f / sqrtf(t * t + 1.f);
            float s = t * c;
            for (int k = 0; k < 3; k++) { float akp = A[k][p], akq = A[k][q]; A[k][p] = c*akp - s*akq; A[k][q] = s*akp + c*akq; }
            for (int k = 0; k < 3; k++) { float apk = A[p][k], aqk = A[q][k]; A[p][k] = c*apk - s*aqk; A[q][k] = s*apk + c*aqk; }
            for (int k = 0; k < 3; k++) { float vkp = V[k][p], vkq = V[k][q]; V[k][p] = c*vkp - s*vkq; V[k][q] = s*vkp + c*vkq; }
        }
    }
    float lam[3] = { A[0][0], A[1][1], A[2][2] };
    int ord[3] = { 0, 1, 2 };
    if (lam[ord[1]] > lam[ord[0]]) { int t0 = ord[0]; ord[0] = ord[1]; ord[1] = t0; }
    if (lam[ord[2]] > lam[ord[0]]) { int t0 = ord[0]; ord[0] = ord[2]; ord[2] = t0; }
    if (lam[ord[2]] > lam[ord[1]]) { int t0 = ord[1]; ord[1] = ord[2]; ord[2] = t0; }
    float vc[3][3], uc[3][3];
    for (int i = 0; i < 3; i++) { vc[i][0] = V[0][ord[i]]; vc[i][1] = V[1][ord[i]]; vc[i][2] = V[2][ord[i]]; }
    for (int i = 0; i < 3; i++) {
        float u0 = H[0][0]*vc[i][0] + H[0][1]*vc[i][1] + H[0][2]*vc[i][2];
        float u1 = H[1][0]*vc[i][0] + H[1][1]*vc[i][1] + H[1][2]*vc[i][2];
        float u2 = H[2][0]*vc[i][0] + H[2][1]*vc[i][1] + H[2][2]*vc[i][2];
        for (int j = 0; j < i; j++) {
            float dp = u0*uc[j][0] + u1*uc[j][1] + u2*uc[j][2];
            u0 -= dp*uc[j][0]; u1 -= dp*uc[j][1]; u2 -= dp*uc[j][2];
        }
        float nn2 = sqrtf(u0*u0 + u1*u1 + u2*u2);
        if (nn2 > 1e-12f) { uc[i][0] = u0/nn2; uc[i][1] = u1/nn2; uc[i][2] = u2/nn2; }
        else if (i == 2) {
            uc[2][0] = uc[0][1]*uc[1][2] - uc[0][2]*uc[1][1];
            uc[2][1] = uc[0][2]*uc[1][0] - uc[0][0]*uc[1][2];
            uc[2][2] = uc[0][0]*uc[1][1] - uc[0][1]*uc[1][0];
        } else if (i == 1) {
            float a0 = (fabsf(uc[0][0]) < 0.9f) ? 1.f : 0.f, a1 = 1.f - a0, a2 = 0.f;
            float dp = a0*uc[0][0] + a1*uc[0][1] + a2*uc[0][2];
            a0 -= dp*uc[0][0]; a1 -= dp*uc[0][1]; a2 -= dp*uc[0][2];
            float nn3 = sqrtf(a0*a0 + a1*a1 + a2*a2);
            uc[1][0] = a0/nn3; uc[1][1] = a1/nn3; uc[1][2] = a2/nn3;
        } else { uc[0][0] = 1; uc[0][1] = 0; uc[0][2] = 0; }
    }
    float detU = uc[0][0]*(uc[1][1]*uc[2][2] - uc[1][2]*uc[2][1])
               - uc[0][1]*(uc[1][0]*uc[2][2] - uc[1][2]*uc[2][0])
               + uc[0][2]*(uc[1][0]*uc[2][1] - uc[1][1]*uc[2][0]);
    float detV = vc[0][0]*(vc[1][1]*vc[2][2] - vc[1][2]*vc[2][1])
               - vc[0][1]*(vc[1][0]*vc[2][2] - vc[1][2]*vc[2][0])
               + vc[0][2]*(vc[1][0]*vc[2][1] - vc[1][1]*vc[2][0]);
    float sgn = (detU * detV < 0.f) ? -1.f : 1.f;
    double R[3][3];
    for (int i = 0; i < 3; i++)
        for (int j = 0; j < 3; j++)
            R[i][j] = (double)(vc[0][i]*uc[0][j] + vc[1][i]*uc[1][j] + sgn * vc[2][i]*uc[2][j]);
    double tr0 = cc0 - (R[0][0]*cs0 + R[0][1]*cs1 + R[0][2]*cs2);
    double tr1 = cc1 - (R[1][0]*cs0 + R[1][1]*cs1 + R[1][2]*cs2);
    double tr2 = cc2 - (R[2][0]*cs0 + R[2][1]*cs1 + R[2][2]*cs2);
    double Ao[12];
#pragma unroll
    for (int k = 0; k < 12; k++) Ao[k] = T[g * 12 + k];
    double An[12];
    for (int i = 0; i < 3; i++)
        for (int j = 0; j < 3; j++)
            An[i*3+j] = R[i][0]*Ao[0*3+j] + R[i][1]*Ao[1*3+j] + R[i][2]*Ao[2*3+j];
    An[9]  = R[0][0]*Ao[9] + R[0][1]*Ao[10] + R[0][2]*Ao[11] + tr0;
    An[10] = R[1][0]*Ao[9] + R[1][1]*Ao[10] + R[1][2]*Ao[11] + tr1;
    An[11] = R[2][0]*Ao[9] + R[2][1]*Ao[10] + R[2][2]*Ao[11] + tr2;
#pragma unroll
    for (int k = 0; k < 12; k++) T[g * 12 + k] = An[k];
}

__global__ void k_icp_apply(const float* __restrict__ tpos, const double* __restrict__ T,
                            float* __restrict__ out)
{
    int n = blockIdx.x * 256 + threadIdx.x;
    if (n >= N_NODES) return;
    int g = n >> 11;
    const double* Tg = &T[g * 12];
    double px = tpos[n*3+0], py = tpos[n*3+1], pz = tpos[n*3+2];
    out[n*3+0] = (float)(Tg[0]*px + Tg[1]*py + Tg[2]*pz + Tg[9]);
    out[n*3+1] = (float)(Tg[3]*px + Tg[4]*py + Tg[5]*pz + Tg[10]);
    out[n*3+2] = (float)(Tg[6]*px + Tg[7]*py + Tg[8]*pz + Tg[11]);
}

__global__ __launch_bounds__(512) void k_chamfer(const float* __restrict__ Apts,
        const float* __restrict__ Btgt, float* __restrict__ part)
{
    const int g = blockIdx.x >> 5, blk = blockIdx.x & 31;
    __shared__ float4 tq4s[NPG_];
    __shared__ float redd[64 * 65];
    const int tid = threadIdx.x;
    for (int i = tid; i < NPG_; i += 512) {
        const float* p = &Btgt[(size_t)(g * NPG_ + i) * 3];
        tq4s[i] = make_float4(p[0], p[1], p[2], 0.f);
    }
    __syncthreads();
    const int sg = tid & 7, q = tid >> 3, j0 = q * 32;
    float Xs[8], Ys[8], Zs[8], bd[8];
#pragma unroll
    for (int u = 0; u < 8; u++) {
        int n = g * NPG_ + blk * 64 + sg * 8 + u;
        Xs[u] = Apts[n*3+0]; Ys[u] = Apts[n*3+1]; Zs[u] = Apts[n*3+2];
        bd[u] = 1e30f;
    }
    for (int j = 0; j < 32; j++) {
        float4 t4 = tq4s[j0 + j];
#pragma unroll
        for (int u = 0; u < 8; u++) {
            float dx = Xs[u] - t4.x, dy = Ys[u] - t4.y, dz = Zs[u] - t4.z;
            bd[u] = fminf(bd[u], fmaf(dx, dx, fmaf(dy, dy, dz * dz)));
        }
    }
#pragma unroll
    for (int u = 0; u < 8; u++) redd[(sg * 8 + u) * 65 + q] = bd[u];
    __syncthreads();
    if (tid < 64) {
        float m = redd[tid * 65];
        for (int r = 1; r < 64; r++) m = fminf(m, redd[tid * 65 + r]);
        for (int o = 32; o > 0; o >>= 1) m += __shfl_down(m, o);
        if (tid == 0) part[blockIdx.x] = m;
    }
}

__global__ void k_loss(const float* __restrict__ pA, const float* __restrict__ pB,
                       float* __restrict__ out)
{
    if (threadIdx.x == 0 && blockIdx.x == 0) {
        double acc = 0;
        for (int g = 0; g < B_GRAPHS; ++g) {
            double s1 = 0, s2 = 0;
            for (int b = 0; b < NN_BPG; b++) { s1 += pA[g*NN_BPG + b]; s2 += pB[g*NN_BPG + b]; }
            acc += s1 / (double)NPG_ + s2 / (double)NPG_;
        }
        out[0] = (float)(acc / (double)B_GRAPHS);
    }
}

extern "C" void kernel_launch(void* const* d_in, const int* in_sizes, int n_in,
                              void* d_out, int out_size, void* d_ws, size_t ws_size,
                              hipStream_t stream)
{
    (void)in_sizes; (void)n_in; (void)out_size; (void)ws_size;
    const float* x   = (const float*)d_in[0];
    const int*   ei  = (const int*)d_in[1];
    const float* pos = (const float*)d_in[2];
    const float* W1 = (const float*)d_in[4];
    const float* b1 = (const float*)d_in[5];
    const float* W2 = (const float*)d_in[6];
    const float* b2 = (const float*)d_in[7];
    const float* W3 = (const float*)d_in[8];
    const float* b3 = (const float*)d_in[9];
    const float* Wt = (const float*)d_in[10];
    const float* bt = (const float*)d_in[11];
    const int* row = ei;
    const int* col = ei + E_EDGES;

    char* wsb = (char*)d_ws;
    size_t off_b = 0;
    auto alloc = [&](size_t bytes) -> void* {
        void* p = wsb + off_b;
        off_b = (off_b + bytes + 255) & ~(size_t)255;
        return p;
    };
    int*    counts   = (int*)alloc((size_t)N_NODES * 4);
    int*    offs     = (int*)alloc((size_t)(N_NODES + 1) * 4);
    int*    cursor   = (int*)alloc((size_t)N_NODES * 4);
    int*    srcid    = (int*)alloc((size_t)E_EDGES * 4);
    float*  normv    = (float*)alloc((size_t)E_EDGES * 4);
    float*  dinv     = (float*)alloc((size_t)N_NODES * 4);
    unsigned short* xb  = (unsigned short*)alloc((size_t)N_NODES * F_IN * 2);
    unsigned short* W1b = (unsigned short*)alloc((size_t)F_IN * F_HID * 2);
    unsigned short* W2b = (unsigned short*)alloc((size_t)F_HID * F_HID * 2);
    unsigned short* W3b = (unsigned short*)alloc((size_t)F_HID * F_OUT * 2);
    unsigned short* bufA = (unsigned short*)alloc((size_t)N_NODES * F_HID * 2);
    unsigned short* bufB = (unsigned short*)alloc((size_t)N_NODES * F_HID * 2);
    unsigned short* bufC = (unsigned short*)alloc((size_t)N_NODES * F_HID * 2);
    float*  tpos     = (float*)alloc((size_t)N_NODES * 3 * 4);
    double* T        = (double*)alloc((size_t)B_GRAPHS * 12 * 8);
    float*  partials = (float*)alloc((size_t)B_GRAPHS * NN_BPG * 15 * 4);
    float*  chA      = (float*)alloc((size_t)B_GRAPHS * NN_BPG * 4);
    float*  chB      = (float*)alloc((size_t)B_GRAPHS * NN_BPG * 4);

    float* out_h       = (float*)d_out;
    float* out_aligned = out_h + (size_t)N_NODES * F_OUT;
    float* out_loss    = out_aligned + (size_t)N_NODES * 3;

    k_f2b<<<(N_NODES * F_IN / 4 + 255) / 256, 256, 0, stream>>>(x, xb, N_NODES * F_IN / 4);
    k_wconv<<<(F_IN * F_HID + 255) / 256, 256, 0, stream>>>(W1, W1b, F_IN, F_HID, 8);
    k_wconv<<<(F_HID * F_HID + 255) / 256, 256, 0, stream>>>(W2, W2b, F_HID, F_HID, 8);
    k_wconv<<<(F_HID * F_OUT + 255) / 256, 256, 0, stream>>>(W3, W3b, F_HID, F_OUT, 7);

    hipMemsetAsync(counts, 0, (size_t)N_NODES * 4, stream);
    k_count<<<E_EDGES / 256, 256, 0, stream>>>(col, counts);
    k_scan<<<1, 1024, 0, stream>>>(counts, offs, cursor, dinv);
    k_scatter<<<E_EDGES / 256, 256, 0, stream>>>(row, col, cursor, dinv, srcid, normv);

    // layer 1: relu((A_hat x) @ W1 + b1)
    k_agg<F_IN, 0><<<N_NODES, F_IN / 2, 0, stream>>>(xb, bufA, offs, srcid, normv, dinv, nullptr, 0);
    {
        dim3 grid(F_HID / 64, N_NODES / 128);
        k_gemm_bf16<<<grid, 256, 0, stream>>>(bufA, W1b, b1, bufB, N_NODES, F_HID, F_IN, 1);
    }
    // layer 2: relu(A_hat (h1 @ W2) + b2)
    {
        dim3 grid(F_HID / 64, N_NODES / 128);
        k_gemm_bf16<<<grid, 256, 0, stream>>>(bufB, W2b, nullptr, bufC, N_NODES, F_HID, F_HID, 0);
    }
    k_agg<F_HID, 0><<<N_NODES, F_HID / 2, 0, stream>>>(bufC, bufA, offs, srcid, normv, dinv, b2, 1);
    // layer 3: A_hat (h2 @ W3) + b3
    {
        dim3 grid(F_OUT / 64, N_NODES / 128);
        k_gemm_bf16<<<grid, 256, 0, stream>>>(bufA, W3b, nullptr, bufB, N_NODES, F_OUT, F_HID, 0);
    }
    k_agg<F_OUT, 1><<<N_NODES, F_OUT / 2, 0, stream>>>(bufB, out_h, offs, srcid, normv, dinv, b3, 0);

    k_tpos<<<N_NODES / 4, 256, 0, stream>>>(out_h, Wt, bt, pos, tpos);

    k_icp_init<<<1, 128, 0, stream>>>(T);
    for (int it = 0; it < ICP_IT; ++it) {
        k_icp_nn<<<B_GRAPHS * NN_BPG, 512, 0, stream>>>(tpos, pos, T, partials);
        k_icp_svd<<<1, 64, 0, stream>>>(partials, T);
    }
    k_icp_apply<<<N_NODES / 256, 256, 0, stream>>>(tpos, T, out_aligned);

    k_chamfer<<<B_GRAPHS * NN_BPG, 512, 0, stream>>>(out_aligned, pos, chA);
    k_chamfer<<<B_GRAPHS * NN_BPG, 512, 0, stream>>>(pos, out_aligned, chB);
    k_loss<<<1, 64, 0, stream>>>(chA, chB, out_loss);
}